// Round 6
// baseline (185.597 us; speedup 1.0000x reference)
//
#include <hip/hip_runtime.h>
#include <vector>
#include <cmath>
#include <cstdint>

// ---------------------------------------------------------------------------
// Sparse Clebsch-Gordan tensor product, LMAX=5, TAUS=16, BATCH=256.
//
// R6: latency attack.
//  - Per-job term table {xrow,yrow,coeff} padded to multiples of 4; inner
//    loop is a compile-time 4-unrolled "quad" -> 8 independent F-loads issued
//    together (4x memory-level parallelism), no serial address arithmetic.
//  - batch/jid are wave-uniform by construction (58,496 and 128 are multiples
//    of 64); readfirstlane forces them scalar so job/term/coeff traffic goes
//    through the scalar path (SGPRs), leaving VMEM for F-loads + stores.
//  - Keeps R5's dense-sweep grid-stride output mapping (best so far).
// ---------------------------------------------------------------------------

#define LMAXV 5
#define NTAU 16

static const int CUMT[7] = {0, 16, 64, 144, 256, 400, 576};
constexpr int F_ROWS  = 576;                      // complex rows per batch
constexpr int NBATCH  = 256;
constexpr uint32_t F4_PER_BATCH = 457u * 128u;    // 58,496 float4 per batch
constexpr uint32_t NTOT = F4_PER_BATCH * NBATCH;  // 14,974,976 float4
constexpr int GRID = 2048, BLK = 256;

struct Job2 { int term_off; int nquad; };         // terms padded to 4*nquad

typedef float f32x4 __attribute__((ext_vector_type(4)));

// ------------------------- host-side CG table build ------------------------

static double factd(int n) { double r = 1.0; for (int i = 2; i <= n; ++i) r *= (double)i; return r; }

static double cg_coef(int j1, int m1, int j2, int m2, int j, int m) {
    if (m1 + m2 != m) return 0.0;
    double pref = std::sqrt((2.0 * j + 1.0) * factd(j + j1 - j2) * factd(j - j1 + j2) *
                            factd(j1 + j2 - j) / factd(j1 + j2 + j + 1));
    pref *= std::sqrt(factd(j + m) * factd(j - m) * factd(j1 - m1) * factd(j1 + m1) *
                      factd(j2 - m2) * factd(j2 + m2));
    int kmin = std::max(0, std::max(j2 - j - m1, j1 + m2 - j));
    int kmax = std::min(j1 + j2 - j, std::min(j1 - m1, j2 + m2));
    double s = 0.0;
    for (int k = kmin; k <= kmax; ++k) {
        s += ((k & 1) ? -1.0 : 1.0) /
             (factd(k) * factd(j1 + j2 - j - k) * factd(j1 - m1 - k) * factd(j2 + m2 - k) *
              factd(j - j2 + m1 + k) * factd(j - j1 - m2 + k));
    }
    return pref * s;
}

struct Tables { std::vector<Job2> jobs; std::vector<uint2> terms; };

static const Tables& get_tables() {
    static Tables t = []() {
        Tables t;
        for (int l = 0; l <= LMAXV; ++l) {
            for (int m_idx = 0; m_idx < 2 * l + 1; ++m_idx) {
                int m = m_idx - l;
                for (int l1 = 0; l1 <= LMAXV; ++l1) {
                    for (int l2 = l1; l2 <= LMAXV; ++l2) {
                        if (!(std::abs(l1 - l2) <= l && l <= l1 + l2)) continue;
                        int lo = std::max(-l1, m - l2), hi = std::min(l1, m + l2);
                        int cnt = hi - lo + 1;                       // <= 11
                        Job2 jb;
                        jb.term_off = (int)t.terms.size();
                        jb.nquad    = (cnt + 3) / 4;
                        for (int k = 0; k < jb.nquad * 4; ++k) {
                            uint2 tm;
                            if (k < cnt) {
                                int m1 = lo + k;
                                uint32_t xr = (uint32_t)(CUMT[l1] + (m1 + l1) * NTAU);
                                uint32_t yr = (uint32_t)(CUMT[l2] + (m - m1 + l2) * NTAU);
                                float c = (float)cg_coef(l1, m1, l2, m - m1, l, m);
                                tm.x = xr | (yr << 16);
                                tm.y = __builtin_bit_cast(uint32_t, c);
                            } else {
                                tm.x = 0; tm.y = 0;                   // row 0, coeff 0
                            }
                            t.terms.push_back(tm);
                        }
                        t.jobs.push_back(jb);
                    }
                }
            }
        }
        return t;
    }();
    return t;
}

// --------------------------------- kernel ----------------------------------

__global__ __launch_bounds__(256) void cg_tp_kernel(
    const char* __restrict__ Fs, f32x4* __restrict__ out,
    const Job2* __restrict__ jobs, const uint2* __restrict__ terms)
{
    const uint32_t lane = threadIdx.x & 63u;
    const uint32_t G    = (uint32_t)GRID * BLK;

    for (uint32_t g = (uint32_t)blockIdx.x * BLK + threadIdx.x; g < NTOT; g += G) {
        // wave-uniform decode (58,496 and 128 are multiples of 64)
        const uint32_t g0    = __builtin_amdgcn_readfirstlane(g & ~63u);
        const uint32_t batch = g0 / F4_PER_BATCH;
        const uint32_t rem0  = g0 - batch * F4_PER_BATCH;
        const uint32_t jid   = rem0 >> 7;
        const uint32_t half  = (rem0 >> 6) & 1u;

        const uint32_t w  = half * 64u + lane;
        const uint32_t i  = w >> 3;          // tau1 0..15
        const uint32_t jp = w & 7u;          // tau2 pair 0..7
        const uint32_t offA = i * 8u;        // byte offset for a
        const uint32_t offV = jp * 16u;      // byte offset for v

        const Job2 jb = jobs[jid];                                // scalar
        const char* __restrict__ F = Fs + (size_t)batch * (F_ROWS * 8);  // scalar base

        float aR0 = 0.f, aI0 = 0.f, aR1 = 0.f, aI1 = 0.f;
        for (int q = 0; q < jb.nquad; ++q) {
            #pragma unroll
            for (int u = 0; u < 4; ++u) {
                const uint2 tm = terms[jb.term_off + q * 4 + u];  // scalar
                const uint32_t xb = (tm.x & 0xffffu) * 8u;        // byte row offs
                const uint32_t yb = (tm.x >> 16) * 8u;
                const float    c  = __builtin_bit_cast(float, tm.y);
                const float2 a = *(const float2*)(F + xb + offA);
                const f32x4  v = *(const f32x4*)(F + yb + offV);
                aR0 = fmaf(c, a.x * v.x - a.y * v.y, aR0);
                aI0 = fmaf(c, a.x * v.y + a.y * v.x, aI0);
                aR1 = fmaf(c, a.x * v.z - a.y * v.w, aR1);
                aI1 = fmaf(c, a.x * v.w + a.y * v.z, aI1);
            }
        }
        f32x4 val; val.x = aR0; val.y = aI0; val.z = aR1; val.w = aI1;
        out[g] = val;
    }
}

// ------------------------------ entry point --------------------------------

extern "C" void kernel_launch(void* const* d_in, const int* in_sizes, int n_in,
                              void* d_out, int out_size, void* d_ws, size_t ws_size,
                              hipStream_t stream) {
    const Tables& t = get_tables();

    char*  ws       = (char*)d_ws;
    Job2*  d_jobs   = (Job2*)ws;
    size_t jbytes   = t.jobs.size() * sizeof(Job2);
    size_t toff     = (jbytes + 255) & ~(size_t)255;
    uint2* d_terms  = (uint2*)(ws + toff);

    hipMemcpyAsync(d_jobs, t.jobs.data(), jbytes, hipMemcpyHostToDevice, stream);
    hipMemcpyAsync(d_terms, t.terms.data(), t.terms.size() * sizeof(uint2),
                   hipMemcpyHostToDevice, stream);

    const char* Fs  = (const char*)d_in[0];
    f32x4*      out = (f32x4*)d_out;

    cg_tp_kernel<<<GRID, BLK, 0, stream>>>(Fs, out, d_jobs, d_terms);
}